// Round 1
// baseline (188.368 us; speedup 1.0000x reference)
//
#include <hip/hip_runtime.h>
#include <stdint.h>

#define HWPOS 1024
#define CCH   256
#define RROWS 128   // 2B
#define EPSF  1.1920928955078125e-07f

typedef __attribute__((ext_vector_type(8))) short   short8;
typedef __attribute__((ext_vector_type(4))) float   float4v;

__device__ __forceinline__ unsigned short f2bf(float f) {
  uint32_t x = __float_as_uint(f);
  x += 0x7FFFu + ((x >> 16) & 1u);          // RNE bf16
  return (unsigned short)(x >> 16);
}

// ---------------------------------------------------------------------------
// Kernel 1: transpose [B,C,H,W] f32 -> ws[hw][r][c] bf16, with 16B-chunk
// swizzle inside each 512B row: data chunk c stored at slot c ^ (r&7).
// Block: r fixed (0..127), 32 hw positions, all 256 channels.
// ---------------------------------------------------------------------------
__global__ __launch_bounds__(256) void k_transpose(const float* __restrict__ inp,
                                                   const float* __restrict__ tgt,
                                                   unsigned short* __restrict__ wsF) {
  __shared__ float lbuf[256 * 36];          // [c][hw(32)+pad4] = 36.9 KB
  const int t   = threadIdx.x;
  const int r   = blockIdx.y;
  const int hw0 = blockIdx.x * 32;
  const float* src = (r < 64) ? (inp + (size_t)r * CCH * HWPOS)
                              : (tgt + (size_t)(r - 64) * CCH * HWPOS);
  // phase A: coalesced float4 loads over hw, store [c][hw] in LDS
  {
    const int hq = t & 7;                   // hw quad (8 -> 32 hw)
    const int cc = t >> 3;                  // 0..31
#pragma unroll
    for (int ci = 0; ci < 8; ++ci) {
      int c = ci * 32 + cc;
      float4 g = *(const float4*)(src + (size_t)c * HWPOS + hw0 + hq * 4);
      *(float4*)&lbuf[c * 36 + hq * 4] = g;
    }
  }
  __syncthreads();
  // phase B: read 8 c-values per lane, cvt bf16, 16B store (chunk-swizzled)
  const int m  = r & 7;
  const int j  = t & 7;
  const int h  = t >> 3;                    // 0..31
#pragma unroll
  for (int g = 0; g < 4; ++g) {
    int slot = g * 8 + j;                   // destination 16B chunk (0..31)
    int c8   = g * 8 + (j ^ m);             // source data chunk
    float v[8];
#pragma unroll
    for (int e = 0; e < 8; ++e) v[e] = lbuf[(c8 * 8 + e) * 36 + h];
    uint4 o;
    o.x = f2bf(v[0]) | ((uint32_t)f2bf(v[1]) << 16);
    o.y = f2bf(v[2]) | ((uint32_t)f2bf(v[3]) << 16);
    o.z = f2bf(v[4]) | ((uint32_t)f2bf(v[5]) << 16);
    o.w = f2bf(v[6]) | ((uint32_t)f2bf(v[7]) << 16);
    size_t base = ((size_t)(hw0 + h) * RROWS + r) * CCH + slot * 8;
    *(uint4*)(wsF + base) = o;
  }
}

// ---------------------------------------------------------------------------
// Kernel 2: one block per hw. Stage 64KB bf16 image, gram via MFMA,
// norms from diagonal, fused masked log-softmax + pos extraction.
// 8 waves; wave w owns G row-tile w (16 rows) x all 8 col-tiles.
// ---------------------------------------------------------------------------
__global__ __launch_bounds__(512, 4) void k_gram(const unsigned short* __restrict__ wsF,
                                                 float* __restrict__ partials) {
  __shared__ unsigned short Fs[RROWS * CCH];   // 64 KB, swizzled image
  __shared__ float sInv[RROWS];
  __shared__ float wred[8];
  const int t  = threadIdx.x;
  const int hw = blockIdx.x;
  // stage ws[hw] -> LDS (contiguous, coalesced)
  {
    const int4* g4 = (const int4*)(wsF + (size_t)hw * (RROWS * CCH));
    int4* l4 = (int4*)Fs;
#pragma unroll
    for (int it = 0; it < 8; ++it) l4[it * 512 + t] = g4[it * 512 + t];
  }
  __syncthreads();
  const int lane = t & 63;
  const int w    = t >> 6;        // wave id 0..7 = row-tile
  const int lid  = lane & 15;
  const int quad = lane >> 4;
  const int lm   = lid & 7;       // r&7 for every row this lane touches
  float4v acc[8];
#pragma unroll
  for (int ni = 0; ni < 8; ++ni) acc[ni] = (float4v){0.f, 0.f, 0.f, 0.f};
  const int baseA = ((w << 4) | lid) * CCH;
#pragma unroll
  for (int ks = 0; ks < 8; ++ks) {
    const int off = (((ks * 4 + quad) ^ lm) << 3);   // swizzled slot offset
    short8 a = *(const short8*)&Fs[baseA + off];
#pragma unroll
    for (int ni = 0; ni < 8; ++ni) {
      short8 b = *(const short8*)&Fs[((ni << 4) | lid) * CCH + off];
      acc[ni] = __builtin_amdgcn_mfma_f32_16x16x32_bf16(a, b, acc[ni], 0, 0, 0);
    }
  }
  // inverse norms from diag (tile ni==w; lanes with lid>>2 == quad hold it)
  if ((lid >> 2) == quad) {
    float nrm = fmaxf(sqrtf(acc[w][lid & 3]), EPSF);
    sInv[(w << 4) | lid] = 1.0f / nrm;
  }
  __syncthreads();
  float invj[8];
#pragma unroll
  for (int ni = 0; ni < 8; ++ni) invj[ni] = sInv[(ni << 4) | lid];
  float lacc = 0.f;
#pragma unroll
  for (int reg = 0; reg < 4; ++reg) {
    const int rloc = quad * 4 + reg;           // local row in tile
    const int rg   = (w << 4) | rloc;          // global row 0..127
    const float invi = sInv[rg];
    float v[8];
#pragma unroll
    for (int ni = 0; ni < 8; ++ni) v[ni] = 2.0f * acc[ni][reg] * invi * invj[ni];
    if (lid == rloc) v[w] = -3.0e38f;          // mask self-similarity
    float mx = v[0];
#pragma unroll
    for (int ni = 1; ni < 8; ++ni) mx = fmaxf(mx, v[ni]);
#pragma unroll
    for (int s = 1; s < 16; s <<= 1) mx = fmaxf(mx, __shfl_xor(mx, s, 16));
    float sm = 0.f;
#pragma unroll
    for (int ni = 0; ni < 8; ++ni) sm += expf(v[ni] - mx);
#pragma unroll
    for (int s = 1; s < 16; s <<= 1) sm += __shfl_xor(sm, s, 16);
    const float lse = mx + logf(sm);
    const int jp = (rg + 64) & 127;            // positive-pair column
    const float cand = v[jp >> 4];
    const float vp = __shfl(cand, jp & 15, 16);
    lacc += vp - lse;                          // log_softmax at partner (x16 lanes)
  }
#pragma unroll
  for (int s = 1; s < 64; s <<= 1) lacc += __shfl_xor(lacc, s, 64);
  if (lane == 0) wred[w] = lacc;
  __syncthreads();
  if (t == 0) {
    float tot = 0.f;
#pragma unroll
    for (int i = 0; i < 8; ++i) tot += wred[i];
    partials[hw] = tot;                        // = 16 * sum_rows(pos) for this hw
  }
}

// ---------------------------------------------------------------------------
// Kernel 3: reduce 1024 partials -> scalar loss
// ---------------------------------------------------------------------------
__global__ __launch_bounds__(256) void k_reduce(const float* __restrict__ partials,
                                                float* __restrict__ out) {
  __shared__ float wr[4];
  const int t = threadIdx.x;
  float s = 0.f;
#pragma unroll
  for (int i = 0; i < 4; ++i) s += partials[t + i * 256];
#pragma unroll
  for (int sh = 1; sh < 64; sh <<= 1) s += __shfl_xor(s, sh, 64);
  if ((t & 63) == 0) wr[t >> 6] = s;
  __syncthreads();
  if (t == 0) {
    out[0] = -(wr[0] + wr[1] + wr[2] + wr[3]) / (131072.0f * 16.0f);
  }
}

extern "C" void kernel_launch(void* const* d_in, const int* in_sizes, int n_in,
                              void* d_out, int out_size, void* d_ws, size_t ws_size,
                              hipStream_t stream) {
  const float* inp = (const float*)d_in[0];
  const float* tgt = (const float*)d_in[1];
  unsigned short* wsF = (unsigned short*)d_ws;
  float* partials = (float*)((char*)d_ws + (size_t)HWPOS * RROWS * CCH * 2);
  k_transpose<<<dim3(32, 128), 256, 0, stream>>>(inp, tgt, wsF);
  k_gram<<<dim3(HWPOS), 512, 0, stream>>>(wsF, partials);
  k_reduce<<<1, 256, 0, stream>>>(partials, (float*)d_out);
}